// Round 1
// baseline (1958.333 us; speedup 1.0000x reference)
//
#include <hip/hip_runtime.h>
#include <hip/hip_bf16.h>
#include <math.h>

#define BATCH   2
#define LSEQ    16384
#define BLTOK   (BATCH*LSEQ)    // 32768 tokens
#define DMODEL  128
#define DINNER  256
#define DSTATE  64
#define NHEADS  4
#define HEADDIM 64
#define DPROJ   644             // 2*DINNER + 2*DSTATE + NHEADS
#define CCH     384             // DINNER + 2*DSTATE
#define KCONV   4
#define QCH     64              // scan chunk length
#define NCHUNK  (LSEQ/QCH)      // 256
#define NLAYER  4
#define FC1N    512

__device__ __forceinline__ float silu_f(float x){ return x / (1.f + __expf(-x)); }

// ---------------- LayerNorm: one wave per 128-elem row ----------------
__global__ __launch_bounds__(256) void ln_kernel(const float* __restrict__ x,
    const float* __restrict__ w, const float* __restrict__ b, float* __restrict__ out)
{
    int row  = blockIdx.x*4 + (threadIdx.x>>6);
    int lane = threadIdx.x & 63;
    const float* xr = x + (size_t)row*DMODEL;
    float v0 = xr[lane], v1 = xr[lane+64];
    float s = v0 + v1;
    #pragma unroll
    for (int o=32;o;o>>=1) s += __shfl_xor(s,o);
    float mu = s * (1.f/DMODEL);
    float d0 = v0-mu, d1 = v1-mu;
    float q = d0*d0 + d1*d1;
    #pragma unroll
    for (int o=32;o;o>>=1) q += __shfl_xor(q,o);
    float inv = rsqrtf(q*(1.f/DMODEL) + 1e-5f);
    float* op = out + (size_t)row*DMODEL;
    op[lane]    = d0*inv*w[lane]    + b[lane];
    op[lane+64] = d1*inv*w[lane+64] + b[lane+64];
}

// ---------------- Generic fp32 tiled GEMM: C[M,N] (+)= A[M,K]@W[K,N] (+bias) ----------------
template<int K>
__global__ __launch_bounds__(256) void gemm_kernel(
    const float* __restrict__ A, const float* __restrict__ W,
    const float* __restrict__ bias, float* __restrict__ C,
    int N, int accum)
{
    __shared__ __align__(16) float As[16][68];
    __shared__ __align__(16) float Ws[16][68];
    int tid = threadIdx.x;
    int tx = tid & 15, ty = tid >> 4;
    int row0 = blockIdx.y * 64;
    int col0 = blockIdx.x * 64;
    float acc[4][4] = {};
    for (int k0 = 0; k0 < K; k0 += 16) {
        #pragma unroll
        for (int i = 0; i < 4; i++) {      // A tile 64x16 -> As[k][m]
            int e = tid + i*256;
            int r = e >> 4, kk = e & 15;
            As[kk][r] = A[(size_t)(row0 + r)*K + k0 + kk];
        }
        #pragma unroll
        for (int i = 0; i < 4; i++) {      // W tile 16x64
            int e = tid + i*256;
            int kk = e >> 6, c = e & 63;
            int col = col0 + c;
            Ws[kk][c] = (col < N) ? W[(size_t)(k0+kk)*N + col] : 0.f;
        }
        __syncthreads();
        #pragma unroll
        for (int kk = 0; kk < 16; kk++) {
            float4 a = *(const float4*)&As[kk][ty*4];
            float4 w = *(const float4*)&Ws[kk][tx*4];
            float av[4] = {a.x,a.y,a.z,a.w};
            float wv[4] = {w.x,w.y,w.z,w.w};
            #pragma unroll
            for (int i=0;i<4;i++)
              #pragma unroll
              for (int j=0;j<4;j++)
                acc[i][j] += av[i]*wv[j];
        }
        __syncthreads();
    }
    #pragma unroll
    for (int i=0;i<4;i++){
        int r = row0 + ty*4 + i;
        #pragma unroll
        for (int j=0;j<4;j++){
            int c = col0 + tx*4 + j;
            if (c < N) {
                float v = acc[i][j];
                if (bias)  v += bias[c];
                if (accum) v += C[(size_t)r*N + c];
                C[(size_t)r*N + c] = v;
            }
        }
    }
}

// ---------------- dt: softplus(dt_raw + bias), dtA = dt * (-exp(A_log)) ----------------
__global__ __launch_bounds__(256) void dt_kernel(const float* __restrict__ proj,
    const float* __restrict__ dt_bias, const float* __restrict__ A_log,
    float* __restrict__ dt_out, float* __restrict__ dtA_out)
{
    int idx = blockIdx.x*256 + threadIdx.x;
    if (idx >= BLTOK*NHEADS) return;
    int h = idx & 3, t = idx >> 2;
    float v = proj[(size_t)t*DPROJ + 2*DINNER + 2*DSTATE + h] + dt_bias[h];
    float dt = (v > 20.f) ? v : log1pf(__expf(v));
    dt_out[idx]  = dt;
    dtA_out[idx] = -dt * __expf(A_log[h]);
}

// ---------------- causal depthwise conv K=4 + bias + silu ----------------
__global__ __launch_bounds__(384) void conv_kernel(const float* __restrict__ proj,
    const float* __restrict__ cw, const float* __restrict__ cb, float* __restrict__ out)
{
    int ch  = threadIdx.x;
    int tok = blockIdx.x;
    int l = tok & (LSEQ-1);
    const float* base = proj + (size_t)tok*DPROJ + DINNER + ch;
    float acc = cb[ch];
    #pragma unroll
    for (int k=0;k<KCONV;k++){
        int ls = l - (KCONV-1) + k;
        if (ls >= 0) acc += base[(long)(k-(KCONV-1))*DPROJ] * cw[k*CCH+ch];
    }
    out[(size_t)tok*CCH + ch] = silu_f(acc);
}

// ---------------- scan part A: intra-chunk (per b,h,chunk) ----------------
__global__ __launch_bounds__(256) void scan_intra_kernel(
    const float* __restrict__ xBC, const float* __restrict__ dt,
    const float* __restrict__ dtA, float* __restrict__ y,
    float* __restrict__ states, float* __restrict__ Sbuf)
{
    int c  = blockIdx.x;
    int bh = blockIdx.y;           // b*NHEADS + h
    int b = bh >> 2, h = bh & 3;
    int tid = threadIdx.x;
    __shared__ float Xs[QCH][HEADDIM+1];
    __shared__ float Bs[QCH][DSTATE+1];
    __shared__ float Cs[QCH][DSTATE+1];
    __shared__ float Gs[QCH][QCH+1];
    __shared__ float Ss[QCH], dts[QCH], wsd[QCH], dAs[QCH];
    size_t tok0 = (size_t)b*LSEQ + (size_t)c*QCH;

    #pragma unroll
    for (int i=0;i<16;i++){
        int e = tid + i*256;
        int t = e >> 6, j = e & 63;
        const float* rowp = xBC + (tok0 + t)*CCH;
        Xs[t][j] = rowp[h*HEADDIM + j];
        Bs[t][j] = rowp[DINNER + j];
        Cs[t][j] = rowp[DINNER + DSTATE + j];
    }
    if (tid < QCH) {
        dts[tid] = dt [(tok0 + tid)*NHEADS + h];
        dAs[tid] = dtA[(tok0 + tid)*NHEADS + h];
    }
    __syncthreads();
    if (tid == 0) {                 // inclusive cumsum of log-decay
        float run = 0.f;
        for (int t=0;t<QCH;t++){ run += dAs[t]; Ss[t] = run; }
    }
    __syncthreads();
    if (tid < QCH) {
        wsd[tid] = __expf(Ss[QCH-1]-Ss[tid]) * dts[tid];
        Sbuf[(size_t)bh*LSEQ + (size_t)c*QCH + tid] = Ss[tid];
    }
    // G[t][s] = (C_t . B_s) * exp(S_t - S_s) * dt_s  for s<=t
    {
        int bt = tid >> 4, bs = tid & 15;
        float acc[4][4] = {};
        for (int k=0;k<DSTATE;k++){
            float cv[4], bv[4];
            #pragma unroll
            for (int i=0;i<4;i++) cv[i] = Cs[bt*4+i][k];
            #pragma unroll
            for (int j=0;j<4;j++) bv[j] = Bs[bs*4+j][k];
            #pragma unroll
            for (int i=0;i<4;i++)
              #pragma unroll
              for (int j=0;j<4;j++)
                acc[i][j] += cv[i]*bv[j];
        }
        #pragma unroll
        for (int i=0;i<4;i++){
            int t = bt*4+i;
            #pragma unroll
            for (int j=0;j<4;j++){
                int s = bs*4+j;
                Gs[t][s] = (s <= t) ? acc[i][j]*__expf(Ss[t]-Ss[s])*dts[s] : 0.f;
            }
        }
    }
    __syncthreads();
    // Y1 = G @ X
    {
        int bt = tid >> 4, bp = tid & 15;
        float acc[4][4] = {};
        for (int s=0;s<QCH;s++){
            float gv[4], xv[4];
            #pragma unroll
            for (int i=0;i<4;i++) gv[i] = Gs[bt*4+i][s];
            #pragma unroll
            for (int j=0;j<4;j++) xv[j] = Xs[s][bp*4+j];
            #pragma unroll
            for (int i=0;i<4;i++)
              #pragma unroll
              for (int j=0;j<4;j++)
                acc[i][j] += gv[i]*xv[j];
        }
        #pragma unroll
        for (int i=0;i<4;i++){
            int t = bt*4+i;
            size_t o = (tok0 + t)*DINNER + h*HEADDIM + bp*4;
            #pragma unroll
            for (int j=0;j<4;j++) y[o+j] = acc[i][j];
        }
    }
    // local chunk state: st[p][n] = sum_s w_s * X[s][p] * B[s][n]
    {
        int bp = tid >> 4, bn = tid & 15;
        float acc[4][4] = {};
        for (int s=0;s<QCH;s++){
            float w = wsd[s];
            float xv[4], bv[4];
            #pragma unroll
            for (int i=0;i<4;i++) xv[i] = Xs[s][bp*4+i]*w;
            #pragma unroll
            for (int j=0;j<4;j++) bv[j] = Bs[s][bn*4+j];
            #pragma unroll
            for (int i=0;i<4;i++)
              #pragma unroll
              for (int j=0;j<4;j++)
                acc[i][j] += xv[i]*bv[j];
        }
        size_t sb = ((size_t)bh*NCHUNK + c)*HEADDIM*DSTATE;
        #pragma unroll
        for (int i=0;i<4;i++){
            int p = bp*4+i;
            #pragma unroll
            for (int j=0;j<4;j++) states[sb + p*DSTATE + bn*4+j] = acc[i][j];
        }
    }
}

// ---------------- scan part B: inter-chunk recurrence (sequential over 256 chunks) ----------------
__global__ __launch_bounds__(256) void scan_inter_kernel(float* __restrict__ states,
    const float* __restrict__ Sbuf)
{
    int bh   = blockIdx.x >> 4;
    int part = blockIdx.x & 15;
    int pn   = part*256 + threadIdx.x;
    __shared__ float dec[NCHUNK];
    for (int c = threadIdx.x; c < NCHUNK; c += 256)
        dec[c] = __expf(Sbuf[(size_t)bh*LSEQ + (size_t)c*QCH + QCH-1]);
    __syncthreads();
    float hh = 0.f;
    size_t base = (size_t)bh*NCHUNK*HEADDIM*DSTATE + pn;
    #pragma unroll 4
    for (int c=0;c<NCHUNK;c++){
        size_t idx = base + (size_t)c*HEADDIM*DSTATE;
        float loc = states[idx];
        states[idx] = hh;            // overwrite local with h_in(c)
        hh = dec[c]*hh + loc;
    }
}

// ---------------- scan part C: add inter-chunk contribution + D-term + gate ----------------
__global__ __launch_bounds__(256) void scan_apply_kernel(
    float* __restrict__ y, const float* __restrict__ states,
    const float* __restrict__ xBC, const float* __restrict__ proj,
    const float* __restrict__ Sbuf, const float* __restrict__ Dp)
{
    int c = blockIdx.x, bh = blockIdx.y;
    int b = bh >> 2, h = bh & 3;
    int tid = threadIdx.x;
    __shared__ float Cs[QCH][DSTATE+1];
    __shared__ float Hs[HEADDIM][DSTATE+1];
    __shared__ float Es[QCH];
    size_t tok0 = (size_t)b*LSEQ + (size_t)c*QCH;
    #pragma unroll
    for (int i=0;i<16;i++){
        int e = tid + i*256;
        int t = e>>6, j = e&63;
        Cs[t][j] = xBC[(tok0+t)*CCH + DINNER + DSTATE + j];
        Hs[t][j] = states[((size_t)bh*NCHUNK + c)*HEADDIM*DSTATE + (size_t)t*DSTATE + j];
    }
    if (tid < QCH) Es[tid] = __expf(Sbuf[(size_t)bh*LSEQ + (size_t)c*QCH + tid]);
    __syncthreads();
    float dpv = Dp[h];
    int bt = tid>>4, bp = tid&15;
    float acc[4][4] = {};
    for (int n=0;n<DSTATE;n++){
        float cv[4], hv[4];
        #pragma unroll
        for (int i=0;i<4;i++) cv[i] = Cs[bt*4+i][n];
        #pragma unroll
        for (int j=0;j<4;j++) hv[j] = Hs[bp*4+j][n];
        #pragma unroll
        for (int i=0;i<4;i++)
          #pragma unroll
          for (int j=0;j<4;j++)
            acc[i][j] += cv[i]*hv[j];
    }
    #pragma unroll
    for (int i=0;i<4;i++){
        int t = bt*4+i;
        size_t tok = tok0 + t;
        #pragma unroll
        for (int j=0;j<4;j++){
            int p = bp*4+j;
            size_t yi = tok*DINNER + h*HEADDIM + p;
            float y2 = Es[t]*acc[i][j];
            float xh = xBC[tok*CCH + h*HEADDIM + p];
            float z  = proj[tok*DPROJ + h*HEADDIM + p];
            y[yi] = (y[yi] + y2 + dpv*xh) * silu_f(z);
        }
    }
}

// ---------------- GLU: silu(h1)*h2 ----------------
__global__ __launch_bounds__(256) void glu_kernel(const float* __restrict__ h12, float* __restrict__ out)
{
    int tok = blockIdx.x, j = threadIdx.x;
    float h1 = h12[(size_t)tok*FC1N + j];
    float h2 = h12[(size_t)tok*FC1N + 256 + j];
    out[(size_t)tok*DINNER + j] = silu_f(h1)*h2;
}

extern "C" void kernel_launch(void* const* d_in, const int* in_sizes, int n_in,
                              void* d_out, int out_size, void* d_ws, size_t ws_size,
                              hipStream_t stream)
{
    const float* x_in    = (const float*)d_in[0];
    const float* ln1_w   = (const float*)d_in[1];
    const float* ln1_b   = (const float*)d_in[2];
    const float* ln2_w   = (const float*)d_in[3];
    const float* ln2_b   = (const float*)d_in[4];
    const float* in_proj = (const float*)d_in[5];
    const float* conv_w  = (const float*)d_in[6];
    const float* conv_b  = (const float*)d_in[7];
    const float* dt_bias = (const float*)d_in[8];
    const float* A_log   = (const float*)d_in[9];
    const float* Dp      = (const float*)d_in[10];
    const float* out_proj= (const float*)d_in[11];
    const float* fc1_w   = (const float*)d_in[12];
    const float* fc1_b   = (const float*)d_in[13];
    const float* fc2_w   = (const float*)d_in[14];
    const float* fc2_b   = (const float*)d_in[15];

    float* ws = (float*)d_ws;
    float* buf_x    = ws;                                             // 4.19M floats
    float* buf_y    = buf_x    + (size_t)BLTOK*DMODEL;                // 8.39M (aliases x1/x2)
    float* buf_proj = buf_y    + (size_t)BLTOK*DINNER;                // 21.1M
    float* buf_xBC  = buf_proj + (size_t)BLTOK*DPROJ;                 // 12.6M
    float* states   = buf_xBC  + (size_t)BLTOK*CCH;                   // 8.39M
    float* buf_dt   = states   + (size_t)BATCH*NHEADS*NCHUNK*HEADDIM*DSTATE;
    float* buf_dtA  = buf_dt   + (size_t)BLTOK*NHEADS;
    float* Sbuf     = buf_dtA  + (size_t)BLTOK*NHEADS;
    float* t0 = buf_y;   // x1/x2 scratch aliases buf_y (disjoint liveness)

    hipMemcpyAsync(buf_x, x_in, (size_t)BLTOK*DMODEL*sizeof(float),
                   hipMemcpyDeviceToDevice, stream);

    for (int i=0;i<NLAYER;i++){
        ln_kernel<<<BLTOK/4,256,0,stream>>>(buf_x, ln1_w+i*DMODEL, ln1_b+i*DMODEL, t0);
        gemm_kernel<128><<<dim3(11, BLTOK/64),256,0,stream>>>(
            t0, in_proj+(size_t)i*DMODEL*DPROJ, nullptr, buf_proj, DPROJ, 0);
        dt_kernel<<<(BLTOK*NHEADS)/256,256,0,stream>>>(
            buf_proj, dt_bias+i*NHEADS, A_log+i*NHEADS, buf_dt, buf_dtA);
        conv_kernel<<<BLTOK,CCH,0,stream>>>(
            buf_proj, conv_w+(size_t)i*KCONV*CCH, conv_b+(size_t)i*CCH, buf_xBC);
        scan_intra_kernel<<<dim3(NCHUNK, BATCH*NHEADS),256,0,stream>>>(
            buf_xBC, buf_dt, buf_dtA, buf_y, states, Sbuf);
        scan_inter_kernel<<<BATCH*NHEADS*16,256,0,stream>>>(states, Sbuf);
        scan_apply_kernel<<<dim3(NCHUNK, BATCH*NHEADS),256,0,stream>>>(
            buf_y, states, buf_xBC, buf_proj, Sbuf, Dp+i*NHEADS);
        gemm_kernel<256><<<dim3(2, BLTOK/64),256,0,stream>>>(
            buf_y, out_proj+(size_t)i*DINNER*DMODEL, nullptr, buf_x, DMODEL, 1);
        ln_kernel<<<BLTOK/4,256,0,stream>>>(buf_x, ln2_w+i*DMODEL, ln2_b+i*DMODEL, t0);
        gemm_kernel<128><<<dim3(8, BLTOK/64),256,0,stream>>>(
            t0, fc1_w+(size_t)i*DMODEL*FC1N, fc1_b+(size_t)i*FC1N, buf_proj, FC1N, 0);
        glu_kernel<<<BLTOK,256,0,stream>>>(buf_proj, buf_y);
        gemm_kernel<256><<<dim3(2, BLTOK/64),256,0,stream>>>(
            buf_y, fc2_w+(size_t)i*DINNER*DMODEL, fc2_b+i*DMODEL, buf_x, DMODEL, 1);
    }
    hipMemcpyAsync(d_out, buf_x, (size_t)BLTOK*DMODEL*sizeof(float),
                   hipMemcpyDeviceToDevice, stream);
}

// Round 2
// 1261.525 us; speedup vs baseline: 1.5524x; 1.5524x over previous
//
#include <hip/hip_runtime.h>
#include <hip/hip_bf16.h>
#include <math.h>

#define BATCH   2
#define LSEQ    16384
#define BLTOK   (BATCH*LSEQ)    // 32768 tokens
#define DMODEL  128
#define DINNER  256
#define DSTATE  64
#define NHEADS  4
#define HEADDIM 64
#define DPROJ   644             // 2*DINNER + 2*DSTATE + NHEADS
#define CCH     384             // DINNER + 2*DSTATE
#define KCONV   4
#define QCH     64              // scan chunk length
#define NCHUNK  (LSEQ/QCH)      // 256
#define NLAYER  4
#define FC1N    512

typedef __bf16 bf16x8 __attribute__((ext_vector_type(8)));
typedef float  f32x4  __attribute__((ext_vector_type(4)));

__device__ __forceinline__ float silu_f(float x){ return x / (1.f + __expf(-x)); }

__device__ __forceinline__ unsigned short f2bfu(float f){
    union {float f; uint32_t u;} v; v.f = f;
    return (unsigned short)((v.u + 0x7FFF + ((v.u>>16)&1)) >> 16);
}
__device__ __forceinline__ float bfu2f(unsigned short u){
    union {uint32_t u; float f;} v; v.u = ((uint32_t)u)<<16;
    return v.f;
}

// ---------------- weight convert + transpose: W[K][N] f32 -> Wt[Npad][K] bf16 ----------------
__global__ __launch_bounds__(256) void wconv_kernel(const float* __restrict__ W,
    unsigned short* __restrict__ Wt, int K, int N, int Npad)
{
    int o = blockIdx.x*256 + threadIdx.x;
    if (o >= Npad*K) return;
    int n = o / K, k = o - n*K;
    float f = (n < N) ? W[(size_t)k*N + n] : 0.f;
    Wt[o] = f2bfu(f);
}

// ---------------- LayerNorm: one wave per 128-elem row, bf16 out ----------------
__global__ __launch_bounds__(256) void ln_kernel(const float* __restrict__ x,
    const float* __restrict__ w, const float* __restrict__ b, unsigned short* __restrict__ out)
{
    int row  = blockIdx.x*4 + (threadIdx.x>>6);
    int lane = threadIdx.x & 63;
    const float* xr = x + (size_t)row*DMODEL;
    float2 vv = *(const float2*)(xr + lane*2);
    float s = vv.x + vv.y;
    #pragma unroll
    for (int o=32;o;o>>=1) s += __shfl_xor(s,o);
    float mu = s * (1.f/DMODEL);
    float d0 = vv.x-mu, d1 = vv.y-mu;
    float q = d0*d0 + d1*d1;
    #pragma unroll
    for (int o=32;o;o>>=1) q += __shfl_xor(q,o);
    float inv = rsqrtf(q*(1.f/DMODEL) + 1e-5f);
    float2 ww = *(const float2*)(w + lane*2);
    float2 bb = *(const float2*)(b + lane*2);
    float r0 = d0*inv*ww.x + bb.x;
    float r1 = d1*inv*ww.y + bb.y;
    uint32_t pk = (uint32_t)f2bfu(r0) | ((uint32_t)f2bfu(r1)<<16);
    ((uint32_t*)(out + (size_t)row*DMODEL))[lane] = pk;
}

// ---------------- bf16 MFMA GEMM: C[M,N] (+)= A[M,K] @ Wt[N,K]^T (+bias) ----------------
// 64x64 block tile, 4 waves (2x2), each wave 32x32 via 2x2 mfma_f32_16x16x32_bf16 frags.
// LDS XOR-swizzled on 16B units: slot ^= (row&7)  (T2-style, kills 16-way conflicts).
template<int K>
__global__ __launch_bounds__(256) void gemm_bf16_kernel(
    const unsigned short* __restrict__ A, const unsigned short* __restrict__ Wt,
    const float* __restrict__ bias, float* __restrict__ C,
    const int N, const int accum)
{
    __shared__ __align__(16) char lds[2*64*128*2];   // 32 KB: As + Bs (KTILE=128)
    char* As = lds;
    char* Bs = lds + 64*128*2;
    const int tid = threadIdx.x;
    const int row0 = blockIdx.y*64, col0 = blockIdx.x*64;
    const int wave = tid>>6, lane = tid&63;
    const int wm = wave>>1, wn = wave&1;
    const int frow = lane&15, kgrp = lane>>4;
    f32x4 acc[2][2] = {{{0.f,0.f,0.f,0.f},{0.f,0.f,0.f,0.f}},
                       {{0.f,0.f,0.f,0.f},{0.f,0.f,0.f,0.f}}};
    for (int k0=0; k0<K; k0+=128){
        #pragma unroll
        for (int p=0;p<4;p++){
            int e = tid + p*256;        // 0..1023 16B-chunks
            int r = e>>4, kc = e&15;
            uint4 av = *(const uint4*)(A  + (size_t)(row0+r)*K + k0 + kc*8);
            uint4 bv = *(const uint4*)(Wt + (size_t)(col0+r)*K + k0 + kc*8);
            int sw = (kc ^ (r&7))*16;
            *(uint4*)(As + r*256 + sw) = av;
            *(uint4*)(Bs + r*256 + sw) = bv;
        }
        __syncthreads();
        #pragma unroll
        for (int ks=0; ks<4; ks++){
            int kc = ks*4 + kgrp;       // 16B chunk index within row (0..15)
            int ra0 = wm*32 + frow, ra1 = ra0 + 16;
            int rb0 = wn*32 + frow, rb1 = rb0 + 16;
            bf16x8 a0 = *(const bf16x8*)(As + ra0*256 + ((kc ^ (ra0&7))*16));
            bf16x8 a1 = *(const bf16x8*)(As + ra1*256 + ((kc ^ (ra1&7))*16));
            bf16x8 b0 = *(const bf16x8*)(Bs + rb0*256 + ((kc ^ (rb0&7))*16));
            bf16x8 b1 = *(const bf16x8*)(Bs + rb1*256 + ((kc ^ (rb1&7))*16));
            acc[0][0] = __builtin_amdgcn_mfma_f32_16x16x32_bf16(a0,b0,acc[0][0],0,0,0);
            acc[0][1] = __builtin_amdgcn_mfma_f32_16x16x32_bf16(a0,b1,acc[0][1],0,0,0);
            acc[1][0] = __builtin_amdgcn_mfma_f32_16x16x32_bf16(a1,b0,acc[1][0],0,0,0);
            acc[1][1] = __builtin_amdgcn_mfma_f32_16x16x32_bf16(a1,b1,acc[1][1],0,0,0);
        }
        __syncthreads();
    }
    const int crow = (lane>>4)*4, ccol = lane&15;
    #pragma unroll
    for (int fm=0;fm<2;fm++)
    #pragma unroll
    for (int fn=0;fn<2;fn++){
        int gc = col0 + wn*32 + fn*16 + ccol;
        if (gc < N){
            float bv = bias ? bias[gc] : 0.f;
            #pragma unroll
            for (int r=0;r<4;r++){
                int gr = row0 + wm*32 + fm*16 + crow + r;
                size_t idx = (size_t)gr*N + gc;
                float v = acc[fm][fn][r] + bv;
                if (accum) v += C[idx];
                C[idx] = v;
            }
        }
    }
}

// ---------------- dt: softplus(dt_raw + bias), dtA = dt * (-exp(A_log)) ----------------
__global__ __launch_bounds__(256) void dt_kernel(const float* __restrict__ proj,
    const float* __restrict__ dt_bias, const float* __restrict__ A_log,
    float* __restrict__ dt_out, float* __restrict__ dtA_out)
{
    int idx = blockIdx.x*256 + threadIdx.x;
    if (idx >= BLTOK*NHEADS) return;
    int h = idx & 3, t = idx >> 2;
    float v = proj[(size_t)t*DPROJ + 2*DINNER + 2*DSTATE + h] + dt_bias[h];
    float dt = (v > 20.f) ? v : log1pf(__expf(v));
    dt_out[idx]  = dt;
    dtA_out[idx] = -dt * __expf(A_log[h]);
}

// ---------------- causal depthwise conv K=4 + bias + silu ----------------
__global__ __launch_bounds__(384) void conv_kernel(const float* __restrict__ proj,
    const float* __restrict__ cw, const float* __restrict__ cb, float* __restrict__ out)
{
    int ch  = threadIdx.x;
    int tok = blockIdx.x;
    int l = tok & (LSEQ-1);
    const float* base = proj + (size_t)tok*DPROJ + DINNER + ch;
    float acc = cb[ch];
    #pragma unroll
    for (int k=0;k<KCONV;k++){
        int ls = l - (KCONV-1) + k;
        if (ls >= 0) acc += base[(long)(k-(KCONV-1))*DPROJ] * cw[k*CCH+ch];
    }
    out[(size_t)tok*CCH + ch] = silu_f(acc);
}

// ---------------- scan part A: intra-chunk (per b,h,chunk), Y1 -> bf16 ----------------
__global__ __launch_bounds__(256) void scan_intra_kernel(
    const float* __restrict__ xBC, const float* __restrict__ dt,
    const float* __restrict__ dtA, unsigned short* __restrict__ yb,
    float* __restrict__ states, float* __restrict__ Sbuf)
{
    int c  = blockIdx.x;
    int bh = blockIdx.y;           // b*NHEADS + h
    int b = bh >> 2, h = bh & 3;
    int tid = threadIdx.x;
    __shared__ float Xs[QCH][HEADDIM+1];
    __shared__ float Bs[QCH][DSTATE+1];
    __shared__ float Cs[QCH][DSTATE+1];
    __shared__ float Gs[QCH][QCH+1];
    __shared__ float Ss[QCH], dts[QCH], wsd[QCH], dAs[QCH];
    size_t tok0 = (size_t)b*LSEQ + (size_t)c*QCH;

    #pragma unroll
    for (int i=0;i<16;i++){
        int e = tid + i*256;
        int t = e >> 6, j = e & 63;
        const float* rowp = xBC + (tok0 + t)*CCH;
        Xs[t][j] = rowp[h*HEADDIM + j];
        Bs[t][j] = rowp[DINNER + j];
        Cs[t][j] = rowp[DINNER + DSTATE + j];
    }
    if (tid < QCH) {
        dts[tid] = dt [(tok0 + tid)*NHEADS + h];
        dAs[tid] = dtA[(tok0 + tid)*NHEADS + h];
    }
    __syncthreads();
    if (tid == 0) {                 // inclusive cumsum of log-decay
        float run = 0.f;
        for (int t=0;t<QCH;t++){ run += dAs[t]; Ss[t] = run; }
    }
    __syncthreads();
    if (tid < QCH) {
        wsd[tid] = __expf(Ss[QCH-1]-Ss[tid]) * dts[tid];
        Sbuf[(size_t)bh*LSEQ + (size_t)c*QCH + tid] = Ss[tid];
    }
    // G[t][s] = (C_t . B_s) * exp(S_t - S_s) * dt_s  for s<=t
    {
        int bt = tid >> 4, bs = tid & 15;
        float acc[4][4] = {};
        for (int k=0;k<DSTATE;k++){
            float cv[4], bv[4];
            #pragma unroll
            for (int i=0;i<4;i++) cv[i] = Cs[bt*4+i][k];
            #pragma unroll
            for (int j=0;j<4;j++) bv[j] = Bs[bs*4+j][k];
            #pragma unroll
            for (int i=0;i<4;i++)
              #pragma unroll
              for (int j=0;j<4;j++)
                acc[i][j] += cv[i]*bv[j];
        }
        #pragma unroll
        for (int i=0;i<4;i++){
            int t = bt*4+i;
            #pragma unroll
            for (int j=0;j<4;j++){
                int s = bs*4+j;
                Gs[t][s] = (s <= t) ? acc[i][j]*__expf(Ss[t]-Ss[s])*dts[s] : 0.f;
            }
        }
    }
    __syncthreads();
    // Y1 = G @ X  (store bf16)
    {
        int bt = tid >> 4, bp = tid & 15;
        float acc[4][4] = {};
        for (int s=0;s<QCH;s++){
            float gv[4], xv[4];
            #pragma unroll
            for (int i=0;i<4;i++) gv[i] = Gs[bt*4+i][s];
            #pragma unroll
            for (int j=0;j<4;j++) xv[j] = Xs[s][bp*4+j];
            #pragma unroll
            for (int i=0;i<4;i++)
              #pragma unroll
              for (int j=0;j<4;j++)
                acc[i][j] += gv[i]*xv[j];
        }
        #pragma unroll
        for (int i=0;i<4;i++){
            int t = bt*4+i;
            size_t o = (tok0 + t)*DINNER + h*HEADDIM + bp*4;
            uint32_t p0 = (uint32_t)f2bfu(acc[i][0]) | ((uint32_t)f2bfu(acc[i][1])<<16);
            uint32_t p1 = (uint32_t)f2bfu(acc[i][2]) | ((uint32_t)f2bfu(acc[i][3])<<16);
            uint2 pk; pk.x = p0; pk.y = p1;
            *(uint2*)(yb + o) = pk;
        }
    }
    // local chunk state: st[p][n] = sum_s w_s * X[s][p] * B[s][n]
    {
        int bp = tid >> 4, bn = tid & 15;
        float acc[4][4] = {};
        for (int s=0;s<QCH;s++){
            float w = wsd[s];
            float xv[4], bv[4];
            #pragma unroll
            for (int i=0;i<4;i++) xv[i] = Xs[s][bp*4+i]*w;
            #pragma unroll
            for (int j=0;j<4;j++) bv[j] = Bs[s][bn*4+j];
            #pragma unroll
            for (int i=0;i<4;i++)
              #pragma unroll
              for (int j=0;j<4;j++)
                acc[i][j] += xv[i]*bv[j];
        }
        size_t sb = ((size_t)bh*NCHUNK + c)*HEADDIM*DSTATE;
        #pragma unroll
        for (int i=0;i<4;i++){
            int p = bp*4+i;
            #pragma unroll
            for (int j=0;j<4;j++) states[sb + p*DSTATE + bn*4+j] = acc[i][j];
        }
    }
}

// ---------------- scan part B: inter-chunk recurrence (sequential over 256 chunks) ----------------
__global__ __launch_bounds__(256) void scan_inter_kernel(float* __restrict__ states,
    const float* __restrict__ Sbuf)
{
    int bh   = blockIdx.x >> 4;
    int part = blockIdx.x & 15;
    int pn   = part*256 + threadIdx.x;
    __shared__ float dec[NCHUNK];
    for (int c = threadIdx.x; c < NCHUNK; c += 256)
        dec[c] = __expf(Sbuf[(size_t)bh*LSEQ + (size_t)c*QCH + QCH-1]);
    __syncthreads();
    float hh = 0.f;
    size_t base = (size_t)bh*NCHUNK*HEADDIM*DSTATE + pn;
    #pragma unroll 4
    for (int c=0;c<NCHUNK;c++){
        size_t idx = base + (size_t)c*HEADDIM*DSTATE;
        float loc = states[idx];
        states[idx] = hh;            // overwrite local with h_in(c)
        hh = dec[c]*hh + loc;
    }
}

// ---------------- scan part C: add inter-chunk contribution + D-term + gate, in-place bf16 ----------------
__global__ __launch_bounds__(256) void scan_apply_kernel(
    unsigned short* __restrict__ yb, const float* __restrict__ states,
    const float* __restrict__ xBC, const float* __restrict__ proj,
    const float* __restrict__ Sbuf, const float* __restrict__ Dp)
{
    int c = blockIdx.x, bh = blockIdx.y;
    int b = bh >> 2, h = bh & 3;
    int tid = threadIdx.x;
    __shared__ float Cs[QCH][DSTATE+1];
    __shared__ float Hs[HEADDIM][DSTATE+1];
    __shared__ float Es[QCH];
    size_t tok0 = (size_t)b*LSEQ + (size_t)c*QCH;
    #pragma unroll
    for (int i=0;i<16;i++){
        int e = tid + i*256;
        int t = e>>6, j = e&63;
        Cs[t][j] = xBC[(tok0+t)*CCH + DINNER + DSTATE + j];
        Hs[t][j] = states[((size_t)bh*NCHUNK + c)*HEADDIM*DSTATE + (size_t)t*DSTATE + j];
    }
    if (tid < QCH) Es[tid] = __expf(Sbuf[(size_t)bh*LSEQ + (size_t)c*QCH + tid]);
    __syncthreads();
    float dpv = Dp[h];
    int bt = tid>>4, bp = tid&15;
    float acc[4][4] = {};
    for (int n=0;n<DSTATE;n++){
        float cv[4], hv[4];
        #pragma unroll
        for (int i=0;i<4;i++) cv[i] = Cs[bt*4+i][n];
        #pragma unroll
        for (int j=0;j<4;j++) hv[j] = Hs[bp*4+j][n];
        #pragma unroll
        for (int i=0;i<4;i++)
          #pragma unroll
          for (int j=0;j<4;j++)
            acc[i][j] += cv[i]*hv[j];
    }
    #pragma unroll
    for (int i=0;i<4;i++){
        int t = bt*4+i;
        size_t tok = tok0 + t;
        uint2 pk = *(const uint2*)(yb + tok*DINNER + h*HEADDIM + bp*4);
        float y1[4] = { bfu2f((unsigned short)(pk.x & 0xFFFF)),
                        bfu2f((unsigned short)(pk.x >> 16)),
                        bfu2f((unsigned short)(pk.y & 0xFFFF)),
                        bfu2f((unsigned short)(pk.y >> 16)) };
        unsigned short outv[4];
        #pragma unroll
        for (int j=0;j<4;j++){
            int p = bp*4+j;
            float y2 = Es[t]*acc[i][j];
            float xh = xBC[tok*CCH + h*HEADDIM + p];
            float z  = proj[tok*DPROJ + h*HEADDIM + p];
            outv[j] = f2bfu((y1[j] + y2 + dpv*xh) * silu_f(z));
        }
        uint2 po;
        po.x = (uint32_t)outv[0] | ((uint32_t)outv[1]<<16);
        po.y = (uint32_t)outv[2] | ((uint32_t)outv[3]<<16);
        *(uint2*)(yb + tok*DINNER + h*HEADDIM + bp*4) = po;
    }
}

// ---------------- GLU: silu(h1)*h2 -> bf16 ----------------
__global__ __launch_bounds__(256) void glu_kernel(const float* __restrict__ h12,
    unsigned short* __restrict__ out)
{
    int tok = blockIdx.x, j = threadIdx.x;
    float h1 = h12[(size_t)tok*FC1N + j];
    float h2 = h12[(size_t)tok*FC1N + 256 + j];
    out[(size_t)tok*DINNER + j] = f2bfu(silu_f(h1)*h2);
}

extern "C" void kernel_launch(void* const* d_in, const int* in_sizes, int n_in,
                              void* d_out, int out_size, void* d_ws, size_t ws_size,
                              hipStream_t stream)
{
    const float* x_in    = (const float*)d_in[0];
    const float* ln1_w   = (const float*)d_in[1];
    const float* ln1_b   = (const float*)d_in[2];
    const float* ln2_w   = (const float*)d_in[3];
    const float* ln2_b   = (const float*)d_in[4];
    const float* in_proj = (const float*)d_in[5];
    const float* conv_w  = (const float*)d_in[6];
    const float* conv_b  = (const float*)d_in[7];
    const float* dt_bias = (const float*)d_in[8];
    const float* A_log   = (const float*)d_in[9];
    const float* Dp      = (const float*)d_in[10];
    const float* out_proj= (const float*)d_in[11];
    const float* fc1_w   = (const float*)d_in[12];
    const float* fc1_b   = (const float*)d_in[13];
    const float* fc2_w   = (const float*)d_in[14];
    const float* fc2_b   = (const float*)d_in[15];

    float* ws = (float*)d_ws;
    float* buf_x    = ws;                                             // 4.19M f
    float* buf_proj = buf_x    + (size_t)BLTOK*DMODEL;                // 21.1M f (also h12)
    float* buf_xBC  = buf_proj + (size_t)BLTOK*DPROJ;                 // 12.6M f
    float* states   = buf_xBC  + (size_t)BLTOK*CCH;                   // 2.10M f
    float* buf_dt   = states   + (size_t)BATCH*NHEADS*NCHUNK*HEADDIM*DSTATE;
    float* buf_dtA  = buf_dt   + (size_t)BLTOK*NHEADS;
    float* Sbuf     = buf_dtA  + (size_t)BLTOK*NHEADS;
    unsigned short* actb  = (unsigned short*)(Sbuf + (size_t)BATCH*NHEADS*LSEQ); // 8.39M us
    unsigned short* wt_in = actb  + (size_t)BLTOK*DINNER;             // 4*704*128
    unsigned short* wt_out= wt_in + (size_t)NLAYER*704*128;           // 4*128*256
    unsigned short* wt_f1 = wt_out+ (size_t)NLAYER*128*256;           // 4*512*128
    unsigned short* wt_f2 = wt_f1 + (size_t)NLAYER*512*128;           // 4*128*256

    hipMemcpyAsync(buf_x, x_in, (size_t)BLTOK*DMODEL*sizeof(float),
                   hipMemcpyDeviceToDevice, stream);

    // one-time weight convert+transpose (tiny)
    for (int i=0;i<NLAYER;i++){
        wconv_kernel<<<(704*128+255)/256,256,0,stream>>>(
            in_proj + (size_t)i*DMODEL*DPROJ, wt_in + (size_t)i*704*128, DMODEL, DPROJ, 704);
        wconv_kernel<<<(128*256+255)/256,256,0,stream>>>(
            out_proj + (size_t)i*DINNER*DMODEL, wt_out + (size_t)i*128*256, DINNER, DMODEL, 128);
        wconv_kernel<<<(512*128+255)/256,256,0,stream>>>(
            fc1_w + (size_t)i*DMODEL*FC1N, wt_f1 + (size_t)i*512*128, DMODEL, FC1N, 512);
        wconv_kernel<<<(128*256+255)/256,256,0,stream>>>(
            fc2_w + (size_t)i*DINNER*DMODEL, wt_f2 + (size_t)i*128*256, DINNER, DMODEL, 128);
    }

    for (int i=0;i<NLAYER;i++){
        ln_kernel<<<BLTOK/4,256,0,stream>>>(buf_x, ln1_w+i*DMODEL, ln1_b+i*DMODEL, actb);
        gemm_bf16_kernel<128><<<dim3(11, BLTOK/64),256,0,stream>>>(
            actb, wt_in + (size_t)i*704*128, nullptr, buf_proj, DPROJ, 0);
        dt_kernel<<<(BLTOK*NHEADS)/256,256,0,stream>>>(
            buf_proj, dt_bias+i*NHEADS, A_log+i*NHEADS, buf_dt, buf_dtA);
        conv_kernel<<<BLTOK,CCH,0,stream>>>(
            buf_proj, conv_w+(size_t)i*KCONV*CCH, conv_b+(size_t)i*CCH, buf_xBC);
        scan_intra_kernel<<<dim3(NCHUNK, BATCH*NHEADS),256,0,stream>>>(
            buf_xBC, buf_dt, buf_dtA, actb, states, Sbuf);
        scan_inter_kernel<<<BATCH*NHEADS*16,256,0,stream>>>(states, Sbuf);
        scan_apply_kernel<<<dim3(NCHUNK, BATCH*NHEADS),256,0,stream>>>(
            actb, states, buf_xBC, buf_proj, Sbuf, Dp+i*NHEADS);
        gemm_bf16_kernel<256><<<dim3(2, BLTOK/64),256,0,stream>>>(
            actb, wt_out + (size_t)i*128*256, nullptr, buf_x, DMODEL, 1);
        ln_kernel<<<BLTOK/4,256,0,stream>>>(buf_x, ln2_w+i*DMODEL, ln2_b+i*DMODEL, actb);
        gemm_bf16_kernel<128><<<dim3(8, BLTOK/64),256,0,stream>>>(
            actb, wt_f1 + (size_t)i*512*128, fc1_b+(size_t)i*FC1N, buf_proj, FC1N, 0);
        glu_kernel<<<BLTOK,256,0,stream>>>(buf_proj, actb);
        gemm_bf16_kernel<256><<<dim3(2, BLTOK/64),256,0,stream>>>(
            actb, wt_f2 + (size_t)i*128*256, fc2_b+i*DMODEL, buf_x, DMODEL, 1);
    }
    hipMemcpyAsync(d_out, buf_x, (size_t)BLTOK*DMODEL*sizeof(float),
                   hipMemcpyDeviceToDevice, stream);
}

// Round 3
// 1024.993 us; speedup vs baseline: 1.9106x; 1.2308x over previous
//
#include <hip/hip_runtime.h>
#include <hip/hip_bf16.h>
#include <math.h>

#define BATCH   2
#define LSEQ    16384
#define BLTOK   (BATCH*LSEQ)    // 32768 tokens
#define DMODEL  128
#define DINNER  256
#define DSTATE  64
#define NHEADS  4
#define HEADDIM 64
#define DPROJ   644             // 2*DINNER + 2*DSTATE + NHEADS
#define CCH     384             // DINNER + 2*DSTATE
#define KCONV   4
#define QCH     64              // scan chunk length
#define NCHUNK  (LSEQ/QCH)      // 256
#define NLAYER  4
#define FC1N    512

typedef __bf16 bf16x8 __attribute__((ext_vector_type(8)));
typedef float  f32x4  __attribute__((ext_vector_type(4)));

__device__ __forceinline__ float silu_f(float x){ return x / (1.f + __expf(-x)); }

__device__ __forceinline__ unsigned short f2bfu(float f){
    union {float f; uint32_t u;} v; v.f = f;
    return (unsigned short)((v.u + 0x7FFF + ((v.u>>16)&1)) >> 16);
}
__device__ __forceinline__ float bfu2f(unsigned short u){
    union {uint32_t u; float f;} v; v.u = ((uint32_t)u)<<16;
    return v.f;
}
// swizzled byte address in a 64-row x 128B-row LDS tile (16B-chunk XOR)
__device__ __forceinline__ int swza(int r, int bytecol){
    return r*128 + ((((bytecol)>>4)^(r&7))<<4) + ((bytecol)&15);
}

// ---------------- weight convert + transpose: W[K][N] f32 -> Wt[Npad][K] bf16 ----------------
__global__ __launch_bounds__(256) void wconv_kernel(const float* __restrict__ W,
    unsigned short* __restrict__ Wt, int K, int N, int Npad)
{
    int o = blockIdx.x*256 + threadIdx.x;
    if (o >= Npad*K) return;
    int n = o / K, k = o - n*K;
    float f = (n < N) ? W[(size_t)k*N + n] : 0.f;
    Wt[o] = f2bfu(f);
}

// ---------------- LayerNorm: one wave per 128-elem row, bf16 out ----------------
__global__ __launch_bounds__(256) void ln_kernel(const float* __restrict__ x,
    const float* __restrict__ w, const float* __restrict__ b, unsigned short* __restrict__ out)
{
    int row  = blockIdx.x*4 + (threadIdx.x>>6);
    int lane = threadIdx.x & 63;
    const float* xr = x + (size_t)row*DMODEL;
    float2 vv = *(const float2*)(xr + lane*2);
    float s = vv.x + vv.y;
    #pragma unroll
    for (int o=32;o;o>>=1) s += __shfl_xor(s,o);
    float mu = s * (1.f/DMODEL);
    float d0 = vv.x-mu, d1 = vv.y-mu;
    float q = d0*d0 + d1*d1;
    #pragma unroll
    for (int o=32;o;o>>=1) q += __shfl_xor(q,o);
    float inv = rsqrtf(q*(1.f/DMODEL) + 1e-5f);
    float2 ww = *(const float2*)(w + lane*2);
    float2 bb = *(const float2*)(b + lane*2);
    float r0 = d0*inv*ww.x + bb.x;
    float r1 = d1*inv*ww.y + bb.y;
    uint32_t pk = (uint32_t)f2bfu(r0) | ((uint32_t)f2bfu(r1)<<16);
    ((uint32_t*)(out + (size_t)row*DMODEL))[lane] = pk;
}

// ---------------- bf16 MFMA GEMM: C[M,N] (+)= A[M,K] @ Wt[N,K]^T (+bias) ----------------
template<int K>
__global__ __launch_bounds__(256) void gemm_bf16_kernel(
    const unsigned short* __restrict__ A, const unsigned short* __restrict__ Wt,
    const float* __restrict__ bias, float* __restrict__ C,
    const int N, const int accum)
{
    __shared__ __align__(16) char lds[2*64*128*2];   // 32 KB: As + Bs (KTILE=128)
    char* As = lds;
    char* Bs = lds + 64*128*2;
    const int tid = threadIdx.x;
    const int row0 = blockIdx.y*64, col0 = blockIdx.x*64;
    const int wave = tid>>6, lane = tid&63;
    const int wm = wave>>1, wn = wave&1;
    const int frow = lane&15, kgrp = lane>>4;
    f32x4 acc[2][2] = {{{0.f,0.f,0.f,0.f},{0.f,0.f,0.f,0.f}},
                       {{0.f,0.f,0.f,0.f},{0.f,0.f,0.f,0.f}}};
    for (int k0=0; k0<K; k0+=128){
        #pragma unroll
        for (int p=0;p<4;p++){
            int e = tid + p*256;        // 0..1023 16B-chunks
            int r = e>>4, kc = e&15;
            uint4 av = *(const uint4*)(A  + (size_t)(row0+r)*K + k0 + kc*8);
            uint4 bv = *(const uint4*)(Wt + (size_t)(col0+r)*K + k0 + kc*8);
            int sw = (kc ^ (r&7))*16;
            *(uint4*)(As + r*256 + sw) = av;
            *(uint4*)(Bs + r*256 + sw) = bv;
        }
        __syncthreads();
        #pragma unroll
        for (int ks=0; ks<4; ks++){
            int kc = ks*4 + kgrp;
            int ra0 = wm*32 + frow, ra1 = ra0 + 16;
            int rb0 = wn*32 + frow, rb1 = rb0 + 16;
            bf16x8 a0 = *(const bf16x8*)(As + ra0*256 + ((kc ^ (ra0&7))*16));
            bf16x8 a1 = *(const bf16x8*)(As + ra1*256 + ((kc ^ (ra1&7))*16));
            bf16x8 b0 = *(const bf16x8*)(Bs + rb0*256 + ((kc ^ (rb0&7))*16));
            bf16x8 b1 = *(const bf16x8*)(Bs + rb1*256 + ((kc ^ (rb1&7))*16));
            acc[0][0] = __builtin_amdgcn_mfma_f32_16x16x32_bf16(a0,b0,acc[0][0],0,0,0);
            acc[0][1] = __builtin_amdgcn_mfma_f32_16x16x32_bf16(a0,b1,acc[0][1],0,0,0);
            acc[1][0] = __builtin_amdgcn_mfma_f32_16x16x32_bf16(a1,b0,acc[1][0],0,0,0);
            acc[1][1] = __builtin_amdgcn_mfma_f32_16x16x32_bf16(a1,b1,acc[1][1],0,0,0);
        }
        __syncthreads();
    }
    const int crow = (lane>>4)*4, ccol = lane&15;
    #pragma unroll
    for (int fm=0;fm<2;fm++)
    #pragma unroll
    for (int fn=0;fn<2;fn++){
        int gc = col0 + wn*32 + fn*16 + ccol;
        if (gc < N){
            float bv = bias ? bias[gc] : 0.f;
            #pragma unroll
            for (int r=0;r<4;r++){
                int gr = row0 + wm*32 + fm*16 + crow + r;
                size_t idx = (size_t)gr*N + gc;
                float v = acc[fm][fn][r] + bv;
                if (accum) v += C[idx];
                C[idx] = v;
            }
        }
    }
}

// ---------------- causal depthwise conv K=4 + bias + silu ----------------
__global__ __launch_bounds__(384) void conv_kernel(const float* __restrict__ proj,
    const float* __restrict__ cw, const float* __restrict__ cb, float* __restrict__ out)
{
    int ch  = threadIdx.x;
    int tok = blockIdx.x;
    int l = tok & (LSEQ-1);
    const float* base = proj + (size_t)tok*DPROJ + DINNER + ch;
    float acc = cb[ch];
    #pragma unroll
    for (int k=0;k<KCONV;k++){
        int ls = l - (KCONV-1) + k;
        if (ls >= 0) acc += base[(long)(k-(KCONV-1))*DPROJ] * cw[k*CCH+ch];
    }
    out[(size_t)tok*CCH + ch] = silu_f(acc);
}

// ---------------- scan part A: intra-chunk, MFMA (G, Y1, states), dt fused ----------------
__global__ __launch_bounds__(256) void scan_intra_kernel(
    const float* __restrict__ xBC, const float* __restrict__ proj,
    const float* __restrict__ dt_bias, const float* __restrict__ A_log,
    unsigned short* __restrict__ yb, float* __restrict__ states, float* __restrict__ Sbuf)
{
    int c  = blockIdx.x;
    int bh = blockIdx.y;
    int b = bh >> 2, h = bh & 3;
    int tid = threadIdx.x;
    __shared__ __align__(16) char Cl[64*128];
    __shared__ __align__(16) char Bl[64*128];
    __shared__ __align__(16) char Xt[64*128];
    __shared__ __align__(16) char Bw[64*128];
    __shared__ __align__(16) char Gl[64*128];
    __shared__ float Ss[QCH], dts[QCH], wsd[QCH];
    size_t tok0 = (size_t)b*LSEQ + (size_t)c*QCH;

    // stage C,B (row-major) and X (transposed) as bf16 swizzled
    #pragma unroll
    for (int i=0;i<16;i++){
        int e = tid + i*256;
        int s = e >> 6, j = e & 63;
        const float* rp = xBC + (tok0 + s)*CCH;
        float xv = rp[h*HEADDIM + j];
        float bv = rp[DINNER + j];
        float cv = rp[DINNER + DSTATE + j];
        *(unsigned short*)(Cl + swza(s, j*2)) = f2bfu(cv);
        *(unsigned short*)(Bl + swza(s, j*2)) = f2bfu(bv);
        *(unsigned short*)(Xt + swza(j, s*2)) = f2bfu(xv);
    }
    float dAv = 0.f;
    if (tid < QCH){
        float v = proj[(tok0+tid)*DPROJ + 2*DINNER + 2*DSTATE + h] + dt_bias[h];
        float dtv = (v > 20.f) ? v : log1pf(__expf(v));
        dts[tid] = dtv;
        dAv = -dtv * __expf(A_log[h]);
    }
    __syncthreads();
    if (tid < QCH){                 // wave-0 inclusive scan of log-decay
        float val = dAv;
        #pragma unroll
        for (int o=1;o<64;o<<=1){ float nv = __shfl_up(val,o); if (tid >= o) val += nv; }
        Ss[tid] = val;
        Sbuf[(size_t)bh*LSEQ + (size_t)c*QCH + tid] = val;
    }
    __syncthreads();
    if (tid < QCH) wsd[tid] = __expf(Ss[QCH-1]-Ss[tid]) * dts[tid];

    const int wave = tid>>6, lane = tid&63;
    const int wm = wave>>1, wn = wave&1;
    const int frow = lane&15, kg = lane>>4;
    const int crow = (lane>>4)*4, ccol = lane&15;

    // G_raw = C @ B^T
    f32x4 accG[2][2] = {{{0,0,0,0},{0,0,0,0}},{{0,0,0,0},{0,0,0,0}}};
    #pragma unroll
    for (int ks=0; ks<2; ks++){
        int kc = ks*4 + kg;
        int ra0 = wm*32+frow, ra1 = ra0+16, rb0 = wn*32+frow, rb1 = rb0+16;
        bf16x8 a0 = *(const bf16x8*)(Cl + ra0*128 + ((kc^(ra0&7))<<4));
        bf16x8 a1 = *(const bf16x8*)(Cl + ra1*128 + ((kc^(ra1&7))<<4));
        bf16x8 b0 = *(const bf16x8*)(Bl + rb0*128 + ((kc^(rb0&7))<<4));
        bf16x8 b1 = *(const bf16x8*)(Bl + rb1*128 + ((kc^(rb1&7))<<4));
        accG[0][0] = __builtin_amdgcn_mfma_f32_16x16x32_bf16(a0,b0,accG[0][0],0,0,0);
        accG[0][1] = __builtin_amdgcn_mfma_f32_16x16x32_bf16(a0,b1,accG[0][1],0,0,0);
        accG[1][0] = __builtin_amdgcn_mfma_f32_16x16x32_bf16(a1,b0,accG[1][0],0,0,0);
        accG[1][1] = __builtin_amdgcn_mfma_f32_16x16x32_bf16(a1,b1,accG[1][1],0,0,0);
    }
    // decay + causal mask, write G to LDS (bf16 swizzled)
    #pragma unroll
    for (int fm=0;fm<2;fm++)
    #pragma unroll
    for (int fn=0;fn<2;fn++){
        int s_ = wn*32 + fn*16 + ccol;
        #pragma unroll
        for (int r=0;r<4;r++){
            int t_ = wm*32 + fm*16 + crow + r;
            float g = (s_ <= t_) ? accG[fm][fn][r]*__expf(Ss[t_]-Ss[s_])*dts[s_] : 0.f;
            *(unsigned short*)(Gl + swza(t_, s_*2)) = f2bfu(g);
        }
    }
    __syncthreads();   // G ready, wsd ready
    // Bw[n][s] = B[s][n]*wsd[s]
    #pragma unroll
    for (int i=0;i<16;i++){
        int e = tid + i*256;
        int n = e >> 6, s = e & 63;
        float bv = bfu2f(*(const unsigned short*)(Bl + swza(s, n*2)));
        *(unsigned short*)(Bw + swza(n, s*2)) = f2bfu(bv * wsd[s]);
    }
    __syncthreads();
    // Y1 = G @ X (A=G[t][s], B=Xt[p][s]);  states = Xw^T@B (A=Xt[p][s], B=Bw[n][s])
    f32x4 accY[2][2] = {{{0,0,0,0},{0,0,0,0}},{{0,0,0,0},{0,0,0,0}}};
    f32x4 accS[2][2] = {{{0,0,0,0},{0,0,0,0}},{{0,0,0,0},{0,0,0,0}}};
    #pragma unroll
    for (int ks=0; ks<2; ks++){
        int kc = ks*4 + kg;
        int ra0 = wm*32+frow, ra1 = ra0+16, rb0 = wn*32+frow, rb1 = rb0+16;
        bf16x8 g0 = *(const bf16x8*)(Gl + ra0*128 + ((kc^(ra0&7))<<4));
        bf16x8 g1 = *(const bf16x8*)(Gl + ra1*128 + ((kc^(ra1&7))<<4));
        bf16x8 xb0= *(const bf16x8*)(Xt + rb0*128 + ((kc^(rb0&7))<<4));
        bf16x8 xb1= *(const bf16x8*)(Xt + rb1*128 + ((kc^(rb1&7))<<4));
        bf16x8 xa0= *(const bf16x8*)(Xt + ra0*128 + ((kc^(ra0&7))<<4));
        bf16x8 xa1= *(const bf16x8*)(Xt + ra1*128 + ((kc^(ra1&7))<<4));
        bf16x8 w0 = *(const bf16x8*)(Bw + rb0*128 + ((kc^(rb0&7))<<4));
        bf16x8 w1 = *(const bf16x8*)(Bw + rb1*128 + ((kc^(rb1&7))<<4));
        accY[0][0] = __builtin_amdgcn_mfma_f32_16x16x32_bf16(g0,xb0,accY[0][0],0,0,0);
        accY[0][1] = __builtin_amdgcn_mfma_f32_16x16x32_bf16(g0,xb1,accY[0][1],0,0,0);
        accY[1][0] = __builtin_amdgcn_mfma_f32_16x16x32_bf16(g1,xb0,accY[1][0],0,0,0);
        accY[1][1] = __builtin_amdgcn_mfma_f32_16x16x32_bf16(g1,xb1,accY[1][1],0,0,0);
        accS[0][0] = __builtin_amdgcn_mfma_f32_16x16x32_bf16(xa0,w0,accS[0][0],0,0,0);
        accS[0][1] = __builtin_amdgcn_mfma_f32_16x16x32_bf16(xa0,w1,accS[0][1],0,0,0);
        accS[1][0] = __builtin_amdgcn_mfma_f32_16x16x32_bf16(xa1,w0,accS[1][0],0,0,0);
        accS[1][1] = __builtin_amdgcn_mfma_f32_16x16x32_bf16(xa1,w1,accS[1][1],0,0,0);
    }
    size_t sb = ((size_t)bh*NCHUNK + c)*HEADDIM*DSTATE;
    #pragma unroll
    for (int fm=0;fm<2;fm++)
    #pragma unroll
    for (int fn=0;fn<2;fn++){
        int colj = wn*32 + fn*16 + ccol;
        #pragma unroll
        for (int r=0;r<4;r++){
            int rowi = wm*32 + fm*16 + crow + r;
            yb[(tok0+rowi)*DINNER + h*HEADDIM + colj] = f2bfu(accY[fm][fn][r]);
            states[sb + rowi*DSTATE + colj] = accS[fm][fn][r];
        }
    }
}

// ---------------- scan part B: inter-chunk recurrence ----------------
__global__ __launch_bounds__(256) void scan_inter_kernel(float* __restrict__ states,
    const float* __restrict__ Sbuf)
{
    int bh   = blockIdx.x >> 4;
    int part = blockIdx.x & 15;
    int pn   = part*256 + threadIdx.x;
    __shared__ float dec[NCHUNK];
    for (int c = threadIdx.x; c < NCHUNK; c += 256)
        dec[c] = __expf(Sbuf[(size_t)bh*LSEQ + (size_t)c*QCH + QCH-1]);
    __syncthreads();
    float hh = 0.f;
    size_t base = (size_t)bh*NCHUNK*HEADDIM*DSTATE + pn;
    #pragma unroll 4
    for (int c=0;c<NCHUNK;c++){
        size_t idx = base + (size_t)c*HEADDIM*DSTATE;
        float loc = states[idx];
        states[idx] = hh;
        hh = dec[c]*hh + loc;
    }
}

// ---------------- scan part C: y2 = E*(C@H^T) + D-term + gate, MFMA ----------------
__global__ __launch_bounds__(256) void scan_apply_kernel(
    unsigned short* __restrict__ yb, const float* __restrict__ states,
    const float* __restrict__ xBC, const float* __restrict__ proj,
    const float* __restrict__ Sbuf, const float* __restrict__ Dp)
{
    int c = blockIdx.x, bh = blockIdx.y;
    int b = bh >> 2, h = bh & 3;
    int tid = threadIdx.x;
    __shared__ __align__(16) char Cl[64*128];
    __shared__ __align__(16) char Hl[64*128];
    __shared__ float Es[QCH];
    size_t tok0 = (size_t)b*LSEQ + (size_t)c*QCH;
    size_t sb = ((size_t)bh*NCHUNK + c)*HEADDIM*DSTATE;
    #pragma unroll
    for (int i=0;i<16;i++){
        int e = tid + i*256;
        int r = e>>6, j = e&63;
        *(unsigned short*)(Cl + swza(r, j*2)) = f2bfu(xBC[(tok0+r)*CCH + DINNER + DSTATE + j]);
        *(unsigned short*)(Hl + swza(r, j*2)) = f2bfu(states[sb + (size_t)r*DSTATE + j]);
    }
    if (tid < QCH) Es[tid] = __expf(Sbuf[(size_t)bh*LSEQ + (size_t)c*QCH + tid]);
    __syncthreads();
    const int wave = tid>>6, lane = tid&63;
    const int wm = wave>>1, wn = wave&1;
    const int frow = lane&15, kg = lane>>4;
    const int crow = (lane>>4)*4, ccol = lane&15;
    f32x4 acc[2][2] = {{{0,0,0,0},{0,0,0,0}},{{0,0,0,0},{0,0,0,0}}};
    #pragma unroll
    for (int ks=0; ks<2; ks++){
        int kc = ks*4 + kg;
        int ra0 = wm*32+frow, ra1 = ra0+16, rb0 = wn*32+frow, rb1 = rb0+16;
        bf16x8 a0 = *(const bf16x8*)(Cl + ra0*128 + ((kc^(ra0&7))<<4));
        bf16x8 a1 = *(const bf16x8*)(Cl + ra1*128 + ((kc^(ra1&7))<<4));
        bf16x8 b0 = *(const bf16x8*)(Hl + rb0*128 + ((kc^(rb0&7))<<4));
        bf16x8 b1 = *(const bf16x8*)(Hl + rb1*128 + ((kc^(rb1&7))<<4));
        acc[0][0] = __builtin_amdgcn_mfma_f32_16x16x32_bf16(a0,b0,acc[0][0],0,0,0);
        acc[0][1] = __builtin_amdgcn_mfma_f32_16x16x32_bf16(a0,b1,acc[0][1],0,0,0);
        acc[1][0] = __builtin_amdgcn_mfma_f32_16x16x32_bf16(a1,b0,acc[1][0],0,0,0);
        acc[1][1] = __builtin_amdgcn_mfma_f32_16x16x32_bf16(a1,b1,acc[1][1],0,0,0);
    }
    float dpv = Dp[h];
    #pragma unroll
    for (int fm=0;fm<2;fm++)
    #pragma unroll
    for (int fn=0;fn<2;fn++){
        int p = wn*32 + fn*16 + ccol;
        #pragma unroll
        for (int r=0;r<4;r++){
            int t = wm*32 + fm*16 + crow + r;
            size_t tok = tok0 + t;
            size_t yi = tok*DINNER + h*HEADDIM + p;
            float y1 = bfu2f(yb[yi]);
            float xh = xBC[tok*CCH + h*HEADDIM + p];
            float z  = proj[tok*DPROJ + h*HEADDIM + p];
            float v = (y1 + Es[t]*acc[fm][fn][r] + dpv*xh) * silu_f(z);
            yb[yi] = f2bfu(v);
        }
    }
}

// ---------------- GLU: silu(h1)*h2 -> bf16, vectorized x4 ----------------
__global__ __launch_bounds__(256) void glu_kernel(const float* __restrict__ h12,
    unsigned short* __restrict__ out)
{
    int idx = blockIdx.x*256 + threadIdx.x;   // BLTOK*64 quads
    int tok = idx >> 6, q = idx & 63;
    float4 a = *(const float4*)(h12 + (size_t)tok*FC1N + q*4);
    float4 g = *(const float4*)(h12 + (size_t)tok*FC1N + 256 + q*4);
    uint2 pk;
    pk.x = (uint32_t)f2bfu(silu_f(a.x)*g.x) | ((uint32_t)f2bfu(silu_f(a.y)*g.y)<<16);
    pk.y = (uint32_t)f2bfu(silu_f(a.z)*g.z) | ((uint32_t)f2bfu(silu_f(a.w)*g.w)<<16);
    *(uint2*)(out + (size_t)tok*DINNER + q*4) = pk;
}

extern "C" void kernel_launch(void* const* d_in, const int* in_sizes, int n_in,
                              void* d_out, int out_size, void* d_ws, size_t ws_size,
                              hipStream_t stream)
{
    const float* x_in    = (const float*)d_in[0];
    const float* ln1_w   = (const float*)d_in[1];
    const float* ln1_b   = (const float*)d_in[2];
    const float* ln2_w   = (const float*)d_in[3];
    const float* ln2_b   = (const float*)d_in[4];
    const float* in_proj = (const float*)d_in[5];
    const float* conv_w  = (const float*)d_in[6];
    const float* conv_b  = (const float*)d_in[7];
    const float* dt_bias = (const float*)d_in[8];
    const float* A_log   = (const float*)d_in[9];
    const float* Dp      = (const float*)d_in[10];
    const float* out_proj= (const float*)d_in[11];
    const float* fc1_w   = (const float*)d_in[12];
    const float* fc1_b   = (const float*)d_in[13];
    const float* fc2_w   = (const float*)d_in[14];
    const float* fc2_b   = (const float*)d_in[15];

    float* ws = (float*)d_ws;
    float* buf_x    = ws;                                             // 4.19M f
    float* buf_proj = buf_x    + (size_t)BLTOK*DMODEL;                // 21.1M f (also h12)
    float* buf_xBC  = buf_proj + (size_t)BLTOK*DPROJ;                 // 12.6M f
    float* states   = buf_xBC  + (size_t)BLTOK*CCH;                   // 2.10M f
    float* Sbuf     = states   + (size_t)BATCH*NHEADS*NCHUNK*HEADDIM*DSTATE;
    unsigned short* actb  = (unsigned short*)(Sbuf + (size_t)BATCH*NHEADS*LSEQ); // 8.39M us
    unsigned short* wt_in = actb  + (size_t)BLTOK*DINNER;
    unsigned short* wt_out= wt_in + (size_t)NLAYER*704*128;
    unsigned short* wt_f1 = wt_out+ (size_t)NLAYER*128*256;
    unsigned short* wt_f2 = wt_f1 + (size_t)NLAYER*512*128;

    hipMemcpyAsync(buf_x, x_in, (size_t)BLTOK*DMODEL*sizeof(float),
                   hipMemcpyDeviceToDevice, stream);

    for (int i=0;i<NLAYER;i++){
        wconv_kernel<<<(704*128+255)/256,256,0,stream>>>(
            in_proj + (size_t)i*DMODEL*DPROJ, wt_in + (size_t)i*704*128, DMODEL, DPROJ, 704);
        wconv_kernel<<<(128*256+255)/256,256,0,stream>>>(
            out_proj + (size_t)i*DINNER*DMODEL, wt_out + (size_t)i*128*256, DINNER, DMODEL, 128);
        wconv_kernel<<<(512*128+255)/256,256,0,stream>>>(
            fc1_w + (size_t)i*DMODEL*FC1N, wt_f1 + (size_t)i*512*128, DMODEL, FC1N, 512);
        wconv_kernel<<<(128*256+255)/256,256,0,stream>>>(
            fc2_w + (size_t)i*DINNER*DMODEL, wt_f2 + (size_t)i*128*256, DINNER, DMODEL, 128);
    }

    for (int i=0;i<NLAYER;i++){
        ln_kernel<<<BLTOK/4,256,0,stream>>>(buf_x, ln1_w+i*DMODEL, ln1_b+i*DMODEL, actb);
        gemm_bf16_kernel<128><<<dim3(11, BLTOK/64),256,0,stream>>>(
            actb, wt_in + (size_t)i*704*128, nullptr, buf_proj, DPROJ, 0);
        conv_kernel<<<BLTOK,CCH,0,stream>>>(
            buf_proj, conv_w+(size_t)i*KCONV*CCH, conv_b+(size_t)i*CCH, buf_xBC);
        scan_intra_kernel<<<dim3(NCHUNK, BATCH*NHEADS),256,0,stream>>>(
            buf_xBC, buf_proj, dt_bias+i*NHEADS, A_log+i*NHEADS, actb, states, Sbuf);
        scan_inter_kernel<<<BATCH*NHEADS*16,256,0,stream>>>(states, Sbuf);
        scan_apply_kernel<<<dim3(NCHUNK, BATCH*NHEADS),256,0,stream>>>(
            actb, states, buf_xBC, buf_proj, Sbuf, Dp+i*NHEADS);
        gemm_bf16_kernel<256><<<dim3(2, BLTOK/64),256,0,stream>>>(
            actb, wt_out + (size_t)i*128*256, nullptr, buf_x, DMODEL, 1);
        ln_kernel<<<BLTOK/4,256,0,stream>>>(buf_x, ln2_w+i*DMODEL, ln2_b+i*DMODEL, actb);
        gemm_bf16_kernel<128><<<dim3(8, BLTOK/64),256,0,stream>>>(
            actb, wt_f1 + (size_t)i*512*128, fc1_b+(size_t)i*FC1N, buf_proj, FC1N, 0);
        glu_kernel<<<BLTOK*64/256,256,0,stream>>>(buf_proj, actb);
        gemm_bf16_kernel<256><<<dim3(2, BLTOK/64),256,0,stream>>>(
            actb, wt_f2 + (size_t)i*128*256, fc2_b+i*DMODEL, buf_x, DMODEL, 1);
    }
    hipMemcpyAsync(d_out, buf_x, (size_t)BLTOK*DMODEL*sizeof(float),
                   hipMemcpyDeviceToDevice, stream);
}